// Round 1
// baseline (154.857 us; speedup 1.0000x reference)
//
#include <hip/hip_runtime.h>

#define NE 8
#define DIM 1024
#define ALPHA_C 10.0f

__global__ __launch_bounds__(256) void topk_gating_kernel(
    const float* __restrict__ x,
    const float* __restrict__ gw,
    const float* __restrict__ gb,
    float* __restrict__ out,
    int nrows)
{
    __shared__ float wlds[NE * DIM];   // 32 KiB

    const int tid = threadIdx.x;

    // Stage gate weights into LDS (coalesced float4): 2048 float4 / 256 thr = 8 iters
    {
        const float4* src = (const float4*)gw;
        float4* dst = (float4*)wlds;
        #pragma unroll
        for (int i = 0; i < (NE * DIM / 4) / 256; ++i)
            dst[tid + i * 256] = src[tid + i * 256];
    }

    // Bias in registers (uniform scalar loads)
    float bias[NE];
    #pragma unroll
    for (int e = 0; e < NE; ++e) bias[e] = gb[e];

    __syncthreads();

    const int lane = tid & 63;
    const int nwaves = (gridDim.x * blockDim.x) >> 6;
    const int wid = blockIdx.x * (blockDim.x >> 6) + (tid >> 6);

    for (int row = wid; row < nrows; row += nwaves) {
        const float4* xr = (const float4*)(x + (size_t)row * DIM);
        // Coalesced: each j reads 1 KiB contiguous across the wave
        float4 xv0 = xr[lane];
        float4 xv1 = xr[lane + 64];
        float4 xv2 = xr[lane + 128];
        float4 xv3 = xr[lane + 192];

        float acc[NE];
        #pragma unroll
        for (int e = 0; e < NE; ++e) {
            const float4* wr = (const float4*)(wlds + e * DIM);
            float4 w0 = wr[lane];
            float4 w1 = wr[lane + 64];
            float4 w2 = wr[lane + 128];
            float4 w3 = wr[lane + 192];
            float a;
            a  = xv0.x * w0.x + xv0.y * w0.y + xv0.z * w0.z + xv0.w * w0.w;
            a += xv1.x * w1.x + xv1.y * w1.y + xv1.z * w1.z + xv1.w * w1.w;
            a += xv2.x * w2.x + xv2.y * w2.y + xv2.z * w2.z + xv2.w * w2.w;
            a += xv3.x * w3.x + xv3.y * w3.y + xv3.z * w3.z + xv3.w * w3.w;
            acc[e] = a;
        }

        // Full butterfly reduce: afterwards EVERY lane holds the complete sum for each expert
        #pragma unroll
        for (int e = 0; e < NE; ++e) {
            float v = acc[e];
            #pragma unroll
            for (int m = 32; m >= 1; m >>= 1) v += __shfl_xor(v, m);
            acc[e] = v + bias[e];
        }

        // ---- epilogue, redundant on all lanes (all values wave-uniform) ----
        // max and 2nd-largest (duplicate-preserving, matches top_k[:,1])
        float m1 = -INFINITY, m2 = -INFINITY;
        #pragma unroll
        for (int e = 0; e < NE; ++e) {
            float v = acc[e];
            float nm2 = fmaxf(m2, fminf(m1, v));
            m1 = fmaxf(m1, v);
            m2 = nm2;
        }

        // softmax of raw logits
        float ex[NE];
        float sum = 0.f;
        #pragma unroll
        for (int e = 0; e < NE; ++e) {
            ex[e] = __expf(acc[e] - m1);
            sum += ex[e];
        }
        float inv = 1.f / sum;

        // decomposition: mask (l < kth) -> ALPHA*log1p(s), else ALPHA*(exp(s)-1)
        float o[NE];
        #pragma unroll
        for (int e = 0; e < NE; ++e) {
            float s = ex[e] * inv;
            float topv = ALPHA_C * (__expf(s) - 1.f);
            float lowv = ALPHA_C * __logf(1.f + s);
            o[e] = (acc[e] >= m2) ? topv : lowv;
        }

        // final softmax
        float om = o[0];
        #pragma unroll
        for (int e = 1; e < NE; ++e) om = fmaxf(om, o[e]);
        float oex[NE];
        float osum = 0.f;
        #pragma unroll
        for (int e = 0; e < NE; ++e) {
            oex[e] = __expf(o[e] - om);
            osum += oex[e];
        }
        float oinv = 1.f / osum;

        // lane e writes gate[e]; select via compile-time-index chain (no scratch)
        float gsel = oex[0] * oinv;
        #pragma unroll
        for (int e = 1; e < NE; ++e) {
            float ge = oex[e] * oinv;
            gsel = (lane == e) ? ge : gsel;
        }
        if (lane < NE) out[(size_t)row * NE + lane] = gsel;
    }
}

extern "C" void kernel_launch(void* const* d_in, const int* in_sizes, int n_in,
                              void* d_out, int out_size, void* d_ws, size_t ws_size,
                              hipStream_t stream) {
    const float* x  = (const float*)d_in[0];
    const float* gw = (const float*)d_in[1];
    const float* gb = (const float*)d_in[2];
    float* out = (float*)d_out;
    const int nrows = in_sizes[0] / DIM;

    const int block = 256;
    const int grid = 2048;   // 8192 waves -> 16 rows/wave at N=131072
    topk_gating_kernel<<<grid, block, 0, stream>>>(x, gw, gb, out, nrows);
}